// Round 5
// baseline (403.802 us; speedup 1.0000x reference)
//
#include <hip/hip_runtime.h>
#include <hip/hip_bf16.h>

// CausalDiscoveryModule: B=256, N=512, E=32, IN=512, K=10
// out[b,i,j] = gate_b * sigmoid(logit) on per-(b,i)-row top-10 of j, else 0
// logit = sum_e (c_b^2 * emb_i)[e] * emb_j[e]
//
// R10 (base = R9; write/compute overlap):
//  - R9 post-mortem: occupancy 35->59% and VALUBusy 62->75% but SAME time.
//    Model that fits all counters: k2 = compute phase (~120us, VALU-issue
//    bound, HBM idle since emb is L2-resident) + synchronized write burst
//    (262MB / 6.3TB/s = 42us, VALU idle). 120+42=162 ✓; hbm 21% = 42/162 ✓.
//    Grid 2048 = exactly one residency round -> no steady-state staggering;
//    all blocks burst together.
//  - R10: software-pipeline across TWO tiles per block (grid 1024). Tile A's
//    epilogue (8 wave-private LDS-compose phases, barrier-free) is
//    interleaved into tile B's j-scan (one phase per 4 iters): A's 131MB of
//    writes stream during B's compute. Only B's tail burst (~21us) exposed.
//  - Alias care (rowbuf overlays mvv/mjj): barrier after merge-reads before
//    rowbuf scatters; barrier after interleaved A-epilogue before B-publish.
//  - launch_bounds(256,4): +20 VGPR held (ovalA/fjA) across B-scan.

#define NUM_VARS 512
#define EMBED_DIM 32
#define IN_DIM 512
#define BATCH 256

typedef float nf4 __attribute__((ext_vector_type(4)));
typedef float f2 __attribute__((ext_vector_type(2)));

// ---------------- K1: context MLP -> w = c^2 [256][32], gate [256] ----------
__global__ __launch_bounds__(256) void cdm_k1(
    const float* __restrict__ ctx, const float* __restrict__ W1,
    const float* __restrict__ b1, const float* __restrict__ W2,
    const float* __restrict__ b2, const float* __restrict__ Wg,
    const float* __restrict__ bg, float* __restrict__ wws,
    float* __restrict__ gws) {
  const int bb = blockIdx.x;
  const int t = threadIdx.x;
  __shared__ float xs[512];
  __shared__ float psum[32][9];   // +1 pad
  __shared__ float hs[32];
  __shared__ float cs[32];
  const float* x = ctx + (bb << 9);
  xs[t] = x[t];
  xs[t + 256] = x[t + 256];
  __syncthreads();
  {
    const int e = t >> 3, part = t & 7;
    const float* wrow = W1 + e * 512 + part * 64;
    const float* xp = xs + part * 64;
    float a = 0.f;
#pragma unroll
    for (int m = 0; m < 64; ++m) a = fmaf(wrow[m], xp[m], a);
    psum[e][part] = a;
  }
  __syncthreads();
  if (t < 32) {
    float a = 0.f;
#pragma unroll
    for (int p = 0; p < 8; ++p) a += psum[t][p];
    hs[t] = fmaxf(a + b1[t], 0.f);
  }
  __syncthreads();
  if (t < 32) {
    const float* wrow = W2 + (t << 5);
    float a = 0.f;
#pragma unroll
    for (int k = 0; k < 32; ++k) a = fmaf(wrow[k], hs[k], a);
    float c = a + b2[t];
    cs[t] = c;
    wws[(bb << 5) + t] = c * c;
  }
  __syncthreads();
  if (t == 0) {
    float a = 0.f;
#pragma unroll
    for (int k = 0; k < 32; ++k) a = fmaf(Wg[k], cs[k], a);
    float g = a + bg[0];
    gws[bb] = 1.f / (1.f + __expf(-g));
  }
}

// strict-> shift insert: equal values keep earlier-inserted (lower j) above
#define TOP10_INSERT(av, aj, v, jn)                           \
  do {                                                        \
    _Pragma("unroll") for (int k = 9; k >= 1; --k) {          \
      bool gk = (v) > av[k];                                  \
      bool gk1 = (v) > av[k - 1];                             \
      av[k] = gk ? (gk1 ? av[k - 1] : (v)) : av[k];           \
      aj[k] = gk ? (gk1 ? aj[k - 1] : (jn)) : aj[k];          \
    }                                                         \
    bool g0 = (v) > av[0];                                    \
    av[0] = g0 ? (v) : av[0];                                 \
    aj[0] = g0 ? (jn) : aj[0];                                \
  } while (0)

// One 2-row epilogue phase: scatter -> fence -> read+store -> fence -> rezero.
// Wave-private (no barriers). Fences are compile-time only (R6 lesson): they
// stop alias-based reordering of float*-scatter vs nf4*-read; HW DS in-wave
// order provides visibility. Same pattern passed in R8/R9.
__device__ __forceinline__ void epi_phase(
    int p, int q, int lane, int r0t, const float* oval, const int* fjx,
    float* rbw, nf4* rbw4, float* __restrict__ out) {
  const int rbase = (q << 4) | (p << 1);  // block-relative first row (even)
  const bool own = (lane >> 1) == (rbase >> 1);
  const int slot = lane & 1;
  if (own) {
    float* dst = rbw + (slot << 9);
#pragma unroll
    for (int k = 0; k < 10; ++k) dst[fjx[k]] = oval[k];
  }
  asm volatile("" ::: "memory");   // scatter before reads
#pragma unroll
  for (int s = 0; s < 2; ++s) {
    nf4 lo = rbw4[(s << 7) + lane];        // floats [0,256) of row s
    nf4 hi = rbw4[(s << 7) + 64 + lane];   // floats [256,512)
    nf4* ob = reinterpret_cast<nf4*>(out + ((size_t)(r0t + rbase + s) << 9));
    ob[lane] = lo;                         // fully coalesced dwordx4
    ob[lane + 64] = hi;
  }
  asm volatile("" ::: "memory");   // reads before rezero
  if (own) {
    float* dst = rbw + (slot << 9);
#pragma unroll
    for (int k = 0; k < 10; ++k) dst[fjx[k]] = 0.f;
  }
  asm volatile("" ::: "memory");   // rezero before next phase's scatter
}

// j-quarter scan of one 64-row tile; if PIPE, interleave the previous tile's
// epilogue (one 2-row phase per 4 iterations -> 8 phases over 32 iters).
template <bool PIPE>
__device__ __forceinline__ void scan_tile(
    const float* __restrict__ emb, const float* __restrict__ wws, int r0,
    int lane, int jbase, float hv[10], int hj[10],
    int q, int r0A, const float* ovalA, const int* fjA,
    float* rbw, nf4* rbw4, float* __restrict__ out) {
  const int b = r0 >> 9;
  const int i = (r0 + lane) & 511;
  f2 sv2[16];
  {
    const f2* wb = reinterpret_cast<const f2*>(wws + (b << 5));
    const f2* ei = reinterpret_cast<const f2*>(emb + (i << 5));
#pragma unroll
    for (int p = 0; p < 16; ++p) sv2[p] = wb[p] * ei[p];
  }
#pragma unroll
  for (int k = 0; k < 10; ++k) { hv[k] = -1e30f; hj[k] = 0; }

  const nf4* eb4 = reinterpret_cast<const nf4*>(emb);
  for (int tt = 0; tt < 8; ++tt) {
    if constexpr (PIPE) epi_phase(tt, q, lane, r0A, ovalA, fjA, rbw, rbw4, out);
    for (int u = 0; u < 4; ++u) {
      const int t = (tt << 2) | u;
      const int j0 = jbase + (t << 2);
      const nf4* e0 = eb4 + ((j0 + 0) << 3);   // 8 nf4 per emb row
      const nf4* e1 = eb4 + ((j0 + 1) << 3);
      const nf4* e2 = eb4 + ((j0 + 2) << 3);
      const nf4* e3 = eb4 + ((j0 + 3) << 3);
      f2 c0 = {0.f, 0.f}, c1 = {0.f, 0.f}, c2 = {0.f, 0.f}, c3 = {0.f, 0.f};
#pragma unroll
      for (int p = 0; p < 8; ++p) {
        nf4 v0 = e0[p], v1 = e1[p], v2 = e2[p], v3 = e3[p];
        c0 += sv2[2 * p] * __builtin_shufflevector(v0, v0, 0, 1);
        c0 += sv2[2 * p + 1] * __builtin_shufflevector(v0, v0, 2, 3);
        c1 += sv2[2 * p] * __builtin_shufflevector(v1, v1, 0, 1);
        c1 += sv2[2 * p + 1] * __builtin_shufflevector(v1, v1, 2, 3);
        c2 += sv2[2 * p] * __builtin_shufflevector(v2, v2, 0, 1);
        c2 += sv2[2 * p + 1] * __builtin_shufflevector(v2, v2, 2, 3);
        c3 += sv2[2 * p] * __builtin_shufflevector(v3, v3, 0, 1);
        c3 += sv2[2 * p + 1] * __builtin_shufflevector(v3, v3, 2, 3);
      }
      float a0 = c0.x + c0.y, a1 = c1.x + c1.y;
      float a2 = c2.x + c2.y, a3 = c3.x + c3.y;

      const float thr = hv[9];
      int p0 = a0 > thr, p1 = a1 > thr, p2 = a2 > thr, p3 = a3 > thr;
      while (__any(p0 | p1 | p2 | p3)) {
        if (p0 | p1 | p2 | p3) {
          float v;
          int jn;
          if (p0) { v = a0; jn = j0; p0 = 0; }
          else if (p1) { v = a1; jn = j0 + 1; p1 = 0; }
          else if (p2) { v = a2; jn = j0 + 2; p2 = 0; }
          else { v = a3; jn = j0 + 3; p3 = 0; }
          TOP10_INSERT(hv, hj, v, jn);
        }
        const float nt = hv[9];
        p0 = p0 && (a0 > nt);
        p1 = p1 && (a1 > nt);
        p2 = p2 && (a2 > nt);
        p3 = p3 && (a3 > nt);
      }
    }
  }
}

// publish quarter-lists and merge in ascending-j order (exact jax tie order)
__device__ __forceinline__ void publish_and_merge(
    int q, int lane, const float hv[10], const int hj[10],
    float (*mvv)[10][64], unsigned short (*mjj)[10][64],
    float fv[10], int fj[10]) {
#pragma unroll
  for (int k = 0; k < 10; ++k) {
    mvv[q][k][lane] = hv[k];
    mjj[q][k][lane] = (unsigned short)hj[k];
  }
  __syncthreads();
#pragma unroll
  for (int k = 0; k < 10; ++k) {
    fv[k] = mvv[0][k][lane];
    fj[k] = (int)mjj[0][k][lane];
  }
#pragma unroll
  for (int m = 1; m < 4; ++m) {
#pragma unroll
    for (int k = 0; k < 10; ++k) {
      float v = mvv[m][k][lane];
      int jn = (int)mjj[m][k][lane];
      if (v > fv[9]) TOP10_INSERT(fv, fj, v, jn);
    }
  }
}

// ---- K2: 4-wave block; TWO 64-row tiles; A-writes overlap B-compute -------
__global__ __launch_bounds__(256, 4) void cdm_k2(
    const float* __restrict__ emb, const float* __restrict__ wws,
    const float* __restrict__ gws, float* __restrict__ out) {
  const int lane = threadIdx.x & 63;
  const int q = threadIdx.x >> 6;    // wave = j quarter: [128q, 128q+128)
  const int G = __builtin_amdgcn_readfirstlane(blockIdx.x);
  const int jbase = __builtin_amdgcn_readfirstlane(q << 7);

  // union: merge arrays (publish/merge) / row-compose buffer (epilogue)
  //   mvv  [4][10][64] f32 @ 0      = 10240 B
  //   mjj  [4][10][64] u16 @ 10240  =  5120 B
  //   rowbuf [4][2][512] f32 @ 0    = 16384 B
  __shared__ __align__(16) char smem_u[16384];
  float (*mvv)[10][64] = reinterpret_cast<float(*)[10][64]>(smem_u);
  unsigned short (*mjj)[10][64] =
      reinterpret_cast<unsigned short(*)[10][64]>(smem_u + 10240);
  float* rbw = reinterpret_cast<float*>(smem_u) + (q << 10);  // [2][512]
  nf4* rbw4 = reinterpret_cast<nf4*>(rbw);

  float hv[10]; int hj[10];
  float fv[10]; int fj[10];
  const nf4 z4 = {0.f, 0.f, 0.f, 0.f};

  // ================= tile A: rows [r0A, r0A+64) =============================
  const int r0A = G << 6;
  scan_tile<false>(emb, wws, r0A, lane, jbase, hv, hj,
                   q, 0, nullptr, nullptr, nullptr, nullptr, nullptr);
  publish_and_merge(q, lane, hv, hj, mvv, mjj, fv, fj);
  const float gateA = gws[r0A >> 9];
  float ovalA[10]; int fjA[10];
#pragma unroll
  for (int k = 0; k < 10; ++k) {
    ovalA[k] = gateA / (1.f + __expf(-fv[k]));
    fjA[k] = fj[k];
  }
  __syncthreads();   // all merge reads of mvv/mjj done before rowbuf reuse
#pragma unroll
  for (int s = 0; s < 4; ++s) rbw4[(s << 6) + lane] = z4;  // zero wave slice
  asm volatile("" ::: "memory");

  // ============ tile B scan with interleaved tile-A epilogue ================
  const int r0B = r0A + (1 << 16);   // rows [65536+r0A, ...)
  scan_tile<true>(emb, wws, r0B, lane, jbase, hv, hj,
                  q, r0A, ovalA, fjA, rbw, rbw4, out);
  __syncthreads();   // A-epilogue (rowbuf aliases mvv) done before B publish
  publish_and_merge(q, lane, hv, hj, mvv, mjj, fv, fj);
  const float gateB = gws[r0B >> 9];
  float ovalB[10];
#pragma unroll
  for (int k = 0; k < 10; ++k) ovalB[k] = gateB / (1.f + __expf(-fv[k]));
  __syncthreads();   // merge reads done before rowbuf reuse
#pragma unroll
  for (int s = 0; s < 4; ++s) rbw4[(s << 6) + lane] = z4;  // publish dirtied it
  asm volatile("" ::: "memory");

  // ================= tile B epilogue (tail burst, ~21us) ====================
  for (int p = 0; p < 8; ++p)
    epi_phase(p, q, lane, r0B, ovalB, fj, rbw, rbw4, out);
}

extern "C" void kernel_launch(void* const* d_in, const int* in_sizes, int n_in,
                              void* d_out, int out_size, void* d_ws,
                              size_t ws_size, hipStream_t stream) {
  const float* ctx = (const float*)d_in[0];
  const float* emb = (const float*)d_in[1];
  const float* W1 = (const float*)d_in[2];
  const float* b1 = (const float*)d_in[3];
  const float* W2 = (const float*)d_in[4];
  const float* b2 = (const float*)d_in[5];
  const float* Wg = (const float*)d_in[6];
  const float* bg = (const float*)d_in[7];
  float* out = (float*)d_out;
  float* wws = (float*)d_ws;            // 256*32 floats: c^2
  float* gws = wws + BATCH * EMBED_DIM; // 256 floats: gate

  cdm_k1<<<BATCH, 256, 0, stream>>>(ctx, W1, b1, W2, b2, Wg, bg, wws, gws);
  cdm_k2<<<1024, 256, 0, stream>>>(emb, wws, gws, out);
}

// Round 6
// 383.251 us; speedup vs baseline: 1.0536x; 1.0536x over previous
//
#include <hip/hip_runtime.h>
#include <hip/hip_bf16.h>

// CausalDiscoveryModule: B=256, N=512, E=32, IN=512, K=10
// out[b,i,j] = gate_b * sigmoid(logit) on per-(b,i)-row top-10 of j, else 0
// logit = sum_e (c_b^2 * emb_i)[e] * emb_j[e]
//
// R11 (base = R9; R10's fence-pipelined overlap REGRESSED 162->191: in-loop
// asm memory fences blocked load pipelining + occupancy 59->34%):
//  - R8/R9/R10 establish: k2 is instruction-ISSUE bound (insensitive to
//    occupancy 16 vs 32 waves/CU). At 162us, VALUBusy=75% => ~18k instrs
//    issued/wave vs ~8k useful => the while-loop top-10 machinery (priority
//    select ~12 VALU/pass, predicate recompute 8/pass, __any+exec SALU,
//    2 branches/pass, passes = max-over-64-lanes of pending) is the cost.
//  - Fix: TOP10_INSERT is SELF-PREDICATING (v<=hv[9] => all gk false =>
//    no-op), so drop the while loop + priority select entirely: one __any
//    threshold guard per iteration, then 4 unconditional inserts in
//    ascending-j order (identical strict-> tie semantics, bitwise-same list).
//    Merge inserts made unconditional too (drop divergent guards).
//  - Loads back to R8-style f2 (c += sv2[q]*e[q], clean v_pk_fma_f32).
//  - Grid/epilogue = R9 exactly (2048 x 256, 4-wave j-quarters, u16 merge
//    indices, union'd LDS row-compose dense one-pass write).

#define NUM_VARS 512
#define EMBED_DIM 32
#define IN_DIM 512
#define BATCH 256

typedef float nf4 __attribute__((ext_vector_type(4)));
typedef float f2 __attribute__((ext_vector_type(2)));

// ---------------- K1: context MLP -> w = c^2 [256][32], gate [256] ----------
__global__ __launch_bounds__(256) void cdm_k1(
    const float* __restrict__ ctx, const float* __restrict__ W1,
    const float* __restrict__ b1, const float* __restrict__ W2,
    const float* __restrict__ b2, const float* __restrict__ Wg,
    const float* __restrict__ bg, float* __restrict__ wws,
    float* __restrict__ gws) {
  const int bb = blockIdx.x;
  const int t = threadIdx.x;
  __shared__ float xs[512];
  __shared__ float psum[32][9];   // +1 pad
  __shared__ float hs[32];
  __shared__ float cs[32];
  const float* x = ctx + (bb << 9);
  xs[t] = x[t];
  xs[t + 256] = x[t + 256];
  __syncthreads();
  {
    const int e = t >> 3, part = t & 7;
    const float* wrow = W1 + e * 512 + part * 64;
    const float* xp = xs + part * 64;
    float a = 0.f;
#pragma unroll
    for (int m = 0; m < 64; ++m) a = fmaf(wrow[m], xp[m], a);
    psum[e][part] = a;
  }
  __syncthreads();
  if (t < 32) {
    float a = 0.f;
#pragma unroll
    for (int p = 0; p < 8; ++p) a += psum[t][p];
    hs[t] = fmaxf(a + b1[t], 0.f);
  }
  __syncthreads();
  if (t < 32) {
    const float* wrow = W2 + (t << 5);
    float a = 0.f;
#pragma unroll
    for (int k = 0; k < 32; ++k) a = fmaf(wrow[k], hs[k], a);
    float c = a + b2[t];
    cs[t] = c;
    wws[(bb << 5) + t] = c * c;
  }
  __syncthreads();
  if (t == 0) {
    float a = 0.f;
#pragma unroll
    for (int k = 0; k < 32; ++k) a = fmaf(Wg[k], cs[k], a);
    float g = a + bg[0];
    gws[bb] = 1.f / (1.f + __expf(-g));
  }
}

// strict-> shift insert: equal values keep earlier-inserted (lower j) above.
// SELF-PREDICATING: if v <= av[9], every gk is false and nothing changes.
#define TOP10_INSERT(av, aj, v, jn)                           \
  do {                                                        \
    _Pragma("unroll") for (int k = 9; k >= 1; --k) {          \
      bool gk = (v) > av[k];                                  \
      bool gk1 = (v) > av[k - 1];                             \
      av[k] = gk ? (gk1 ? av[k - 1] : (v)) : av[k];           \
      aj[k] = gk ? (gk1 ? aj[k - 1] : (jn)) : aj[k];          \
    }                                                         \
    bool g0 = (v) > av[0];                                    \
    av[0] = g0 ? (v) : av[0];                                 \
    aj[0] = g0 ? (jn) : aj[0];                                \
  } while (0)

// ------- K2: 4-wave block per 64 rows; j-quarter per wave; dense write -----
__global__ __launch_bounds__(256, 8) void cdm_k2(
    const float* __restrict__ emb, const float* __restrict__ wws,
    const float* __restrict__ gws, float* __restrict__ out) {
  const int lane = threadIdx.x & 63;
  const int q = threadIdx.x >> 6;    // wave = j quarter: [128q, 128q+128)
  const int G = __builtin_amdgcn_readfirstlane(blockIdx.x);
  const int r0 = G << 6;             // 64 rows per block, same b
  const int b = r0 >> 9;
  const int i = (r0 + lane) & 511;
  const int jbase = __builtin_amdgcn_readfirstlane(q << 7);

  // union: merge arrays (phase 1) / row-compose buffer (phase 2)
  //   mvv  [4][10][64] f32 @ 0      = 10240 B
  //   mjj  [4][10][64] u16 @ 10240  =  5120 B   (total 15360)
  //   rowbuf [4][2][512] f32 @ 0    = 16384 B
  __shared__ __align__(16) char smem_u[16384];
  float (*mvv)[10][64] = reinterpret_cast<float(*)[10][64]>(smem_u);
  unsigned short (*mjj)[10][64] =
      reinterpret_cast<unsigned short(*)[10][64]>(smem_u + 10240);
  float* rowbuf = reinterpret_cast<float*>(smem_u);

  // sv2[p] = (c^2)[b] * emb[i] as float2 pairs (per-lane)
  f2 sv2[16];
  {
    const f2* wb = reinterpret_cast<const f2*>(wws + (b << 5));
    const f2* ei = reinterpret_cast<const f2*>(emb + (i << 5));
#pragma unroll
    for (int p = 0; p < 16; ++p) sv2[p] = wb[p] * ei[p];
  }
  const float gateb = gws[b];

  float hv[10];
  int hj[10];
#pragma unroll
  for (int k = 0; k < 10; ++k) { hv[k] = -1e30f; hj[k] = 0; }

  const f2* eb = reinterpret_cast<const f2*>(emb);
  for (int t = 0; t < 32; ++t) {
    const int j0 = jbase + (t << 2);
    const f2* e0 = eb + ((j0 + 0) << 4);
    const f2* e1 = eb + ((j0 + 1) << 4);
    const f2* e2 = eb + ((j0 + 2) << 4);
    const f2* e3 = eb + ((j0 + 3) << 4);
    f2 c0 = {0.f, 0.f}, c1 = {0.f, 0.f}, c2 = {0.f, 0.f}, c3 = {0.f, 0.f};
#pragma unroll
    for (int p = 0; p < 16; ++p) {
      c0 += sv2[p] * e0[p];   // v_pk_fma_f32
      c1 += sv2[p] * e1[p];
      c2 += sv2[p] * e2[p];
      c3 += sv2[p] * e3[p];
    }
    float a0 = c0.x + c0.y, a1 = c1.x + c1.y;
    float a2 = c2.x + c2.y, a3 = c3.x + c3.y;

    // one guard, then unconditional self-predicating inserts (ascending j,
    // strict > => exact jax tie order; bitwise-identical list to the old
    // while-loop version, minus all the pass machinery).
    const float thr = hv[9];
    const bool p =
        (a0 > thr) | (a1 > thr) | (a2 > thr) | (a3 > thr);
    if (__any(p)) {
      TOP10_INSERT(hv, hj, a0, j0);
      TOP10_INSERT(hv, hj, a1, j0 + 1);
      TOP10_INSERT(hv, hj, a2, j0 + 2);
      TOP10_INSERT(hv, hj, a3, j0 + 3);
    }
  }

  // ---- publish; every wave builds the final merged list ---------------------
#pragma unroll
  for (int k = 0; k < 10; ++k) {
    mvv[q][k][lane] = hv[k];
    mjj[q][k][lane] = (unsigned short)hj[k];
  }
  __syncthreads();

  // merge 4 quarter-lists in ascending-j order (exact jax tie order):
  // base = list 0, then strict-> insert lists 1,2,3 (self-predicating).
  float fv[10];
  int fj[10];
#pragma unroll
  for (int k = 0; k < 10; ++k) {
    fv[k] = mvv[0][k][lane];
    fj[k] = (int)mjj[0][k][lane];
  }
#pragma unroll
  for (int m = 1; m < 4; ++m) {
#pragma unroll
    for (int k = 0; k < 10; ++k) {
      float v = mvv[m][k][lane];
      int jn = (int)mjj[m][k][lane];
      TOP10_INSERT(fv, fj, v, jn);
    }
  }

  float oval[10];
#pragma unroll
  for (int k = 0; k < 10; ++k) oval[k] = gateb / (1.f + __expf(-fv[k]));

  __syncthreads();   // merge-array reads done before overlay reuse

  // ---- epilogue: batched LDS row compose; dense one-pass coalesced write ---
  // Wave q emits rows r0+16q .. r0+16q+15 in 8 phases of 2 rows:
  //   scatter(2 owner lanes x 10 ds_write) | fence | per row: 2x ds_read_b128
  //   + 2x global_store_dwordx4 | fence | rezero | fence
  // Fences are compile-time only (asm "" memory clobber) to stop alias-based
  // reordering of float*-scatter vs nf4*-read (the R6 bug); HW DS order per
  // wave provides visibility. (Fences sit OUTSIDE the hot scan loop here —
  // R10's mistake was putting them inside it.)
  float* rbw = rowbuf + (q << 10);          // wave-private [2][512]
  nf4* rbw4 = reinterpret_cast<nf4*>(rbw);  // 256 nf4
  {
    const nf4 z4 = {0.f, 0.f, 0.f, 0.f};
#pragma unroll
    for (int s = 0; s < 4; ++s) rbw4[(s << 6) + lane] = z4;
  }
  asm volatile("" ::: "memory");

  for (int p = 0; p < 8; ++p) {
    const int rbase = (q << 4) | (p << 1);  // block-relative first row (even)
    const bool own = (lane >> 1) == (rbase >> 1);
    const int slot = lane & 1;
    if (own) {
      float* dst = rbw + (slot << 9);
#pragma unroll
      for (int k = 0; k < 10; ++k) dst[fj[k]] = oval[k];
    }
    asm volatile("" ::: "memory");   // scatter before reads
#pragma unroll
    for (int s = 0; s < 2; ++s) {
      nf4 lo = rbw4[(s << 7) + lane];        // floats [0,256) of row s
      nf4 hi = rbw4[(s << 7) + 64 + lane];   // floats [256,512)
      nf4* ob = reinterpret_cast<nf4*>(out + ((size_t)(r0 + rbase + s) << 9));
      ob[lane] = lo;                         // fully coalesced dwordx4
      ob[lane + 64] = hi;
    }
    asm volatile("" ::: "memory");   // reads before rezero
    if (own) {
      float* dst = rbw + (slot << 9);
#pragma unroll
      for (int k = 0; k < 10; ++k) dst[fj[k]] = 0.f;
    }
    asm volatile("" ::: "memory");   // rezero before next phase's scatter
  }
}

extern "C" void kernel_launch(void* const* d_in, const int* in_sizes, int n_in,
                              void* d_out, int out_size, void* d_ws,
                              size_t ws_size, hipStream_t stream) {
  const float* ctx = (const float*)d_in[0];
  const float* emb = (const float*)d_in[1];
  const float* W1 = (const float*)d_in[2];
  const float* b1 = (const float*)d_in[3];
  const float* W2 = (const float*)d_in[4];
  const float* b2 = (const float*)d_in[5];
  const float* Wg = (const float*)d_in[6];
  const float* bg = (const float*)d_in[7];
  float* out = (float*)d_out;
  float* wws = (float*)d_ws;            // 256*32 floats: c^2
  float* gws = wws + BATCH * EMBED_DIM; // 256 floats: gate

  cdm_k1<<<BATCH, 256, 0, stream>>>(ctx, W1, b1, W2, b2, Wg, bg, wws, gws);
  cdm_k2<<<2048, 256, 0, stream>>>(emb, wws, gws, out);
}